// Round 6
// baseline (3597.236 us; speedup 1.0000x reference)
//
#include <hip/hip_runtime.h>
#include <math.h>

// ---------------------------------------------------------------------------
// GP posterior mean: separable NUFFT outer products (fp32 atomic-free
// partials) -> fp32 reduce to Toeplitz table vRf (+fp64 rhs) -> 50 x fused CG
// iteration kernels (fp32 Toeplitz MV, fp64 state/scalars, double-buffered)
// -> eval. 1 launch per CG iteration.
// ---------------------------------------------------------------------------

typedef float f2 __attribute__((ext_vector_type(2)));
#define PB 16

__device__ inline f2 f2s(float s) { return (f2){s, s}; }

// exp(i*pi*x*m) with fp64 angle reduction, scaled
__device__ inline f2 phasef(float xv, float m, float scale) {
    double ang = (double)xv * (double)m;
    double r = ang - 2.0 * rint(ang * 0.5);
    float sn, cs;
    sincospif((float)r, &sn, &cs);
    return (f2){cs * scale, sn * scale};
}

// ---------------------------------------------------------------------------
// k_outer: blocks [0,cv) accumulate a private fp32 partial of the raw
// 128x128 v-tile (a,b=127 zero pads); blocks [cv,cv+cf) a private 64x64 Fy
// partial (y folded into dim-1 phase). No atomics, conflict-free LDS.
// v[a,b]  = sum_n exp(i pi x0 (a-63)) exp(i pi x1 (b-63)),  a,b in [0,126]
// Fy[a,b] = sum_n y_n exp(-i pi x0 (a-32)) exp(-i pi x1 (b-32))
// ---------------------------------------------------------------------------
__global__ __launch_bounds__(256, 4) void k_outer(const float* __restrict__ x,
                                                  const float* __restrict__ y,
                                                  float* __restrict__ pv,
                                                  float* __restrict__ pf,
                                                  int N, int cv, int cf)
{
    __shared__ f2 hs[PB][256];
    __shared__ float xs0[PB], xs1[PB], ys[PB];

    int bx = blockIdx.x;
    int t  = threadIdx.x;
    int ty = t >> 4, tx = t & 15;

    if (bx < cv) {
        int CP = (N + cv - 1) / cv;
        int n0 = bx * CP, n1 = min(N, n0 + CP);

        f2 acc[8][8];
        #pragma unroll
        for (int i = 0; i < 8; ++i)
            #pragma unroll
            for (int j = 0; j < 8; ++j) acc[i][j] = (f2){0.f, 0.f};

        for (int s = n0; s < n1; s += PB) {
            int cnt = min(PB, n1 - s);
            __syncthreads();
            if (t < cnt) {
                xs0[t] = x[2 * (s + t)];
                xs1[t] = x[2 * (s + t) + 1];
            }
            __syncthreads();
            for (int p = 0; p < cnt; ++p) {
                f2 g;
                if (t < 128)
                    g = (t == 127) ? (f2){0.f, 0.f} : phasef(xs0[p], (float)t - 63.f, 1.f);
                else {
                    int c = t - 128;
                    g = (c == 127) ? (f2){0.f, 0.f} : phasef(xs1[p], (float)c - 63.f, 1.f);
                }
                hs[p][t] = g;
            }
            __syncthreads();
            for (int p = 0; p < cnt; ++p) {
                f2 h1[8], h2[8], h2s[8];
                #pragma unroll
                for (int i = 0; i < 8; ++i) h1[i] = hs[p][ty * 8 + i];
                #pragma unroll
                for (int j = 0; j < 8; ++j) {
                    f2 b = hs[p][128 + tx + 16 * j];
                    h2[j] = b;
                    h2s[j] = (f2){-b.y, b.x};
                }
                #pragma unroll
                for (int i = 0; i < 8; ++i)
                    #pragma unroll
                    for (int j = 0; j < 8; ++j) {
                        acc[i][j] = acc[i][j] + f2s(h1[i].x) * h2[j];
                        acc[i][j] = acc[i][j] + f2s(h1[i].y) * h2s[j];
                    }
            }
        }
        __syncthreads();
        f2* out = (f2*)pv + (size_t)bx * 16384;
        #pragma unroll
        for (int i = 0; i < 8; ++i) {
            int a = ty * 8 + i;
            #pragma unroll
            for (int j = 0; j < 8; ++j)
                out[a * 128 + tx + 16 * j] = acc[i][j];
        }
    } else {
        int chunk = bx - cv;
        int CP = (N + cf - 1) / cf;
        int n0 = chunk * CP, n1 = min(N, n0 + CP);

        f2 acc[4][4];
        #pragma unroll
        for (int i = 0; i < 4; ++i)
            #pragma unroll
            for (int j = 0; j < 4; ++j) acc[i][j] = (f2){0.f, 0.f};

        for (int s = n0; s < n1; s += PB) {
            int cnt = min(PB, n1 - s);
            __syncthreads();
            if (t < cnt) {
                xs0[t] = x[2 * (s + t)];
                xs1[t] = x[2 * (s + t) + 1];
                ys[t]  = y[s + t];
            }
            __syncthreads();
            for (int p2 = 0; p2 < cnt; p2 += 2) {
                int p = p2 + (t >> 7);
                int c = t & 127;
                if (p < cnt) {
                    f2 g;
                    if (c < 64) g = phasef(xs0[p], (float)(32 - c), ys[p]);
                    else        g = phasef(xs1[p], (float)(32 - (c - 64)), 1.f);
                    hs[p][c] = g;
                }
            }
            __syncthreads();
            for (int p = 0; p < cnt; ++p) {
                f2 h1[4], h2[4], h2s[4];
                #pragma unroll
                for (int i = 0; i < 4; ++i) h1[i] = hs[p][ty * 4 + i];
                #pragma unroll
                for (int j = 0; j < 4; ++j) {
                    f2 b = hs[p][64 + tx + 16 * j];
                    h2[j] = b;
                    h2s[j] = (f2){-b.y, b.x};
                }
                #pragma unroll
                for (int i = 0; i < 4; ++i)
                    #pragma unroll
                    for (int j = 0; j < 4; ++j) {
                        acc[i][j] = acc[i][j] + f2s(h1[i].x) * h2[j];
                        acc[i][j] = acc[i][j] + f2s(h1[i].y) * h2s[j];
                    }
            }
        }
        __syncthreads();
        f2* out = (f2*)pf + (size_t)chunk * 4096;
        #pragma unroll
        for (int i = 0; i < 4; ++i) {
            int a = ty * 4 + i;
            #pragma unroll
            for (int j = 0; j < 4; ++j)
                out[a * 64 + tx + 16 * j] = acc[i][j];
        }
    }
}

// ---------------------------------------------------------------------------
// k_reduce: v partials sliced 8-way per element -> fp32 atomicAdd into
// vRf[(d1+64)*128 + (d2+64)] (zero-initialized; row/col 0 = pads). Fy
// partials serial per element (fp64) -> b = ws*Fy, init r0=p0=b, x0=0, rz0.
// Thread space: [0,131072) = v (elem = id>>3, slice = id&7);
//               [131072,135168) = Fy.
// ---------------------------------------------------------------------------
__global__ __launch_bounds__(256) void k_reduce(const float* __restrict__ pv,
                                                const float* __restrict__ pf,
                                                const float* __restrict__ wsv,
                                                float* __restrict__ vRf,
                                                double2* __restrict__ r0,
                                                double2* __restrict__ p0,
                                                double2* __restrict__ x0,
                                                double* __restrict__ scal,
                                                int cv, int cf)
{
    int id = blockIdx.x * 256 + threadIdx.x;
    if (id < 131072) {
        int e = id >> 3, sl = id & 7;
        int q1 = e >> 7, q2 = e & 127;
        if (q1 >= 1 && q2 >= 1) {
            int cn = cv >> 3;
            const float* src = pv + (size_t)((q1 - 1) * 128 + (q2 - 1)) * 2
                                  + (size_t)(sl * cn) * 32768;
            float sx = 0.f, sy = 0.f;
            for (int c = 0; c < cn; ++c) { sx += src[0]; sy += src[1]; src += 32768; }
            atomicAdd(&vRf[e * 2], sx);
            atomicAdd(&vRf[e * 2 + 1], sy);
        }
    } else {
        int e = id - 131072;          // 0..4095
        const float* s2p = pf + (size_t)e * 2;
        double fx = 0.0, fy2 = 0.0;
        for (int c = 0; c < cf; ++c) { fx += (double)s2p[0]; fy2 += (double)s2p[1]; s2p += 8192; }
        double w = (double)wsv[e];
        double2 bv = make_double2(w * fx, w * fy2);
        r0[e] = bv; p0[e] = bv; x0[e] = make_double2(0.0, 0.0);
        double rr = bv.x * bv.x + bv.y * bv.y;
        for (int off = 32; off > 0; off >>= 1) rr += __shfl_down(rr, off);
        if ((threadIdx.x & 63) == 0) atomicAdd(&scal[0], rr);
    }
}

// ---------------------------------------------------------------------------
// k_cg_iter: one full CG iteration, 256 blocks x 512 threads (8 waves).
//   t==0 recomputes alpha_{it-1}, beta_it from dot history (scal).
//   Replicated fp64 update -> z = ws*p_new stored fp32 in LDS (32 KB).
//   MV: wave w owns rows k = b*16 + 2w + {0,1}; lane = j2, loop j1; per j1
//   one 16B-contiguous vRf load covers both rows; fp32 pk-fma accumulate.
//   Wave-reduce over j2; lane 0 writes Ap/r/p/x (fp64) + dot partials.
//   scal: [0] = rz0; [1+3k..3+3k] = (pAp, rAp, ApAp) of iter k.
//   rz recurrence: rz+ = rz - 2a<r,Ap> + a^2|Ap|^2 (algebraically == ref).
// ---------------------------------------------------------------------------
__global__ __launch_bounds__(512) void k_cg_iter(
        const float* __restrict__ vRf, const float* __restrict__ wsv,
        const float* __restrict__ sig2,
        const double2* __restrict__ pin, double2* __restrict__ pout,
        const double2* __restrict__ rin, double2* __restrict__ rout,
        const double2* __restrict__ xin, double2* __restrict__ xout,
        const double2* __restrict__ apin, double2* __restrict__ apout,
        double* __restrict__ scal, int it)
{
    __shared__ f2 zs[4096];            // 32 KB fp32 z
    __shared__ double s_ab[2];
    __shared__ double redd[8][3];
    int b = blockIdx.x, t = threadIdx.x;

    if (t == 0) {
        double alpha = 0.0, beta = 0.0;
        if (it > 0) {
            double rz = scal[0], rzp = rz, alp = 0.0;
            for (int k = 0; k < it; ++k) {
                double pap = scal[1 + 3 * k], rap = scal[2 + 3 * k], apap = scal[3 + 3 * k];
                double al = rz / (pap + 1e-30);
                rzp = rz; alp = al;
                rz = fma(al, fma(al, apap, -2.0 * rap), rz);
            }
            alpha = alp; beta = rz / (rzp + 1e-30);
        }
        s_ab[0] = alpha; s_ab[1] = beta;
    }
    __syncthreads();
    double alpha = s_ab[0], beta = s_ab[1];

    // replicated update: z = ws * p_new (fp64 math, fp32 store)
    for (int s = 0; s < 8; ++s) {
        int i = t + 512 * s;
        double2 rv = rin[i];
        if (it > 0) {
            double2 ap = apin[i];
            rv.x -= alpha * ap.x; rv.y -= alpha * ap.y;
        }
        double2 pvv = pin[i];
        double2 pn = make_double2(rv.x + beta * pvv.x, rv.y + beta * pvv.y);
        double w = (double)wsv[i];
        zs[i] = (f2){(float)(w * pn.x), (float)(w * pn.y)};
    }
    __syncthreads();

    // fp32 Toeplitz MV: wave w -> rows k2b, k2b+1; lane = j2, loop j1
    int wv = t >> 6, j2 = t & 63;
    int k1 = b >> 2;
    int k2b = (b & 3) * 16 + wv * 2;
    f2 acc0 = (f2){0.f, 0.f}, acc1 = (f2){0.f, 0.f};
    const f2* vb = (const f2*)vRf + (k1 + 64) * 128 + (k2b - j2 + 64);
    const f2* zp = zs + j2;
    #pragma unroll 8
    for (int j1 = 0; j1 < 64; ++j1) {
        f2 zj = zp[j1 * 64];
        f2 zsw = (f2){-zj.y, zj.x};
        const f2* vr = vb - j1 * 128;
        f2 v0 = vr[0], v1 = vr[1];
        acc0 = acc0 + f2s(v0.x) * zj + f2s(v0.y) * zsw;
        acc1 = acc1 + f2s(v1.x) * zj + f2s(v1.y) * zsw;
    }

    #pragma unroll
    for (int off = 32; off > 0; off >>= 1) {
        acc0.x += __shfl_down(acc0.x, off);
        acc0.y += __shfl_down(acc0.y, off);
        acc1.x += __shfl_down(acc1.x, off);
        acc1.y += __shfl_down(acc1.y, off);
    }

    if (j2 == 0) {
        double s2 = (double)sig2[0];
        double d1 = 0.0, d2 = 0.0, d3 = 0.0;
        #pragma unroll
        for (int i = 0; i < 2; ++i) {
            int k = b * 16 + wv * 2 + i;
            double tx = (i == 0) ? (double)acc0.x : (double)acc1.x;
            double tyv = (i == 0) ? (double)acc0.y : (double)acc1.y;
            double2 rv = rin[k];
            if (it > 0) {
                double2 ap = apin[k];
                rv.x -= alpha * ap.x; rv.y -= alpha * ap.y;
            }
            double2 pvv = pin[k];
            double2 pn = make_double2(rv.x + beta * pvv.x, rv.y + beta * pvv.y);
            double w = (double)wsv[k];
            double2 apn = make_double2(w * tx + s2 * pn.x,
                                       w * tyv + s2 * pn.y);
            apout[k] = apn; rout[k] = rv; pout[k] = pn;
            double2 xv = xin[k];
            xout[k] = make_double2(xv.x + alpha * pvv.x, xv.y + alpha * pvv.y);
            d1 += pn.x * apn.x + pn.y * apn.y;
            d2 += rv.x * apn.x + rv.y * apn.y;
            d3 += apn.x * apn.x + apn.y * apn.y;
        }
        redd[wv][0] = d1; redd[wv][1] = d2; redd[wv][2] = d3;
    }
    __syncthreads();
    if (t == 0) {
        double a = 0.0, bb = 0.0, c = 0.0;
        for (int q = 0; q < 8; ++q) { a += redd[q][0]; bb += redd[q][1]; c += redd[q][2]; }
        atomicAdd(&scal[1 + 3 * it], a);
        atomicAdd(&scal[2 + 3 * it], bb);
        atomicAdd(&scal[3 + 3 * it], c);
    }
}

// ---------------------------------------------------------------------------
// k_eval: mu[b] = Re( sum_j e1[j] * sum_k alpha[j,k] e2[k] ),
// alpha = ws * (x_49 + alpha_49 * p_49)  (final CG update folded in).
// ---------------------------------------------------------------------------
__global__ __launch_bounds__(64) void k_eval(const float* __restrict__ xnew,
                                             const float* __restrict__ wsv,
                                             const double2* __restrict__ xsol,
                                             const double2* __restrict__ psol,
                                             const double* __restrict__ scal,
                                             float* __restrict__ out, int B)
{
    __shared__ float2 al[4096];
    __shared__ double s_al;
    int t = threadIdx.x;
    int b = blockIdx.x * 64 + t;
    if (t == 0) {
        double rz = scal[0], alp = 0.0;
        for (int k = 0; k < 50; ++k) {
            double pap = scal[1 + 3 * k], rap = scal[2 + 3 * k], apap = scal[3 + 3 * k];
            double a2 = rz / (pap + 1e-30);
            alp = a2;
            rz = fma(a2, fma(a2, apap, -2.0 * rap), rz);
        }
        s_al = alp;
    }
    __syncthreads();
    double alpha49 = s_al;
    for (int i = t; i < 4096; i += 64) {
        double2 xv = xsol[i];
        double2 pv = psol[i];
        double w = (double)wsv[i];
        al[i] = make_float2((float)(w * (xv.x + alpha49 * pv.x)),
                            (float)(w * (xv.y + alpha49 * pv.y)));
    }
    float x0 = 0.f, x1 = 0.f;
    if (b < B) { x0 = xnew[2 * b]; x1 = xnew[2 * b + 1]; }
    __syncthreads();
    double2 wstep; { double sn, cs; sincospi((double)x1, &sn, &cs); wstep = make_double2(cs, sn); }
    double mu = 0.0;
    for (int jg = 0; jg < 4; ++jg) {
        float2 tacc[16];
        for (int q = 0; q < 16; ++q) tacc[q] = make_float2(0.f, 0.f);
        double2 e2; { double sn, cs; sincospi(-32.0 * (double)x1, &sn, &cs); e2 = make_double2(cs, sn); }
        for (int k = 0; k < 64; ++k) {
            float2 e2f = make_float2((float)e2.x, (float)e2.y);
            for (int q = 0; q < 16; ++q) {
                int j = jg * 16 + q;
                float2 a = al[j * 64 + k];
                tacc[q].x += a.x * e2f.x - a.y * e2f.y;
                tacc[q].y += a.x * e2f.y + a.y * e2f.x;
            }
            e2 = make_double2(e2.x * wstep.x - e2.y * wstep.y,
                              e2.x * wstep.y + e2.y * wstep.x);
        }
        for (int q = 0; q < 16; ++q) {
            int j = jg * 16 + q;
            double sn, cs;
            sincospi((double)x0 * (double)(j - 32), &sn, &cs);
            mu += cs * (double)tacc[q].x - sn * (double)tacc[q].y;
        }
    }
    if (b < B) out[b] = (float)mu;
}

// ---------------------------------------------------------------------------

extern "C" void kernel_launch(void* const* d_in, const int* in_sizes, int n_in,
                              void* d_out, int out_size, void* d_ws, size_t ws_size,
                              hipStream_t stream)
{
    const float* x    = (const float*)d_in[0];
    const float* y    = (const float*)d_in[1];
    const float* xnew = (const float*)d_in[2];
    const float* wsv  = (const float*)d_in[3];
    const float* sig2 = (const float*)d_in[4];
    int N = in_sizes[1];
    int B = in_sizes[2] / 2;

    char* base = (char*)d_ws;
    size_t o = 0;
    float*  vRf  = (float*)(base + o);   o += 131072;    // 128x128 fp32 Toeplitz
    double* scal = (double*)(base + o);  o += 4096;      // [0]=rz0, then 50 triples
    double2* rb[2], *pb[2], *xb[2], *ab[2];
    for (int q = 0; q < 2; ++q) { rb[q] = (double2*)(base + o); o += 65536; }
    for (int q = 0; q < 2; ++q) { pb[q] = (double2*)(base + o); o += 65536; }
    for (int q = 0; q < 2; ++q) { xb[q] = (double2*)(base + o); o += 65536; }
    for (int q = 0; q < 2; ++q) { ab[q] = (double2*)(base + o); o += 65536; }
    size_t avail = (ws_size > o) ? ws_size - o : 0;
    int cv = (int)(avail / 139264);                      // 128KB v + 8KB fy per unit
    if (cv > 384) cv = 384;
    if (cv < 16) cv = 16;
    cv &= ~15;                                           // cv%8==0, cf%4==0
    int cf = cv / 4;
    float* pv = (float*)(base + o); o += (size_t)cv * 131072;
    float* pf = (float*)(base + o);

    hipMemsetAsync(vRf, 0, 131072 + 4096, stream);       // vRf + scal contiguous

    k_outer<<<cv + cf, 256, 0, stream>>>(x, y, pv, pf, N, cv, cf);
    k_reduce<<<528, 256, 0, stream>>>(pv, pf, wsv, vRf,
                                      rb[0], pb[0], xb[0], scal, cv, cf);

    for (int it = 0; it < 50; ++it) {
        int in = it & 1, op = in ^ 1;
        k_cg_iter<<<256, 512, 0, stream>>>(vRf, wsv, sig2,
                                           pb[in], pb[op], rb[in], rb[op],
                                           xb[in], xb[op], ab[in], ab[op],
                                           scal, it);
    }
    // after it=49: final state (x_49, p_49) in parity-0 buffers
    k_eval<<<(B + 63) / 64, 64, 0, stream>>>(xnew, wsv, xb[0], pb[0], scal,
                                             (float*)d_out, B);
}

// Round 7
// 1672.395 us; speedup vs baseline: 2.1509x; 2.1509x over previous
//
#include <hip/hip_runtime.h>
#include <math.h>

// ---------------------------------------------------------------------------
// GP posterior mean: separable NUFFT outer products (fp32 atomic-free
// partials, half-tile blocks for occupancy) -> fp32 reduce to Toeplitz table
// vRf (+fp64 rhs) -> 50 x fused CG iteration kernels (fp32 Toeplitz MV, fp64
// state/scalars, double-buffered) -> eval. 1 launch per CG iteration.
// ---------------------------------------------------------------------------

typedef float f2 __attribute__((ext_vector_type(2)));
#define PB 16

__device__ inline f2 f2s(float s) { return (f2){s, s}; }

// exp(i*pi*x*m) with fp64 angle reduction, scaled
__device__ inline f2 phasef(float xv, float m, float scale) {
    double ang = (double)xv * (double)m;
    double r = ang - 2.0 * rint(ang * 0.5);
    float sn, cs;
    sincospif((float)r, &sn, &cs);
    return (f2){cs * scale, sn * scale};
}

// ---------------------------------------------------------------------------
// k_outer: blocks [0,2*cv): half-tile v blocks (chunk = bx>>1, half = bx&1;
// rows a in [half*64, half*64+64), all 128 cols). acc[4][8] per thread.
// Blocks [2cv, 2cv+cf): 64x64 Fy partial (y folded into dim-1 phase).
// No atomics; conflict-free LDS (h2 lanes consecutive: tx + 16*j).
// v[a,b]  = sum_n exp(i pi x0 (a-63)) exp(i pi x1 (b-63)),  a,b in [0,126]
// Fy[a,b] = sum_n y_n exp(-i pi x0 (a-32)) exp(-i pi x1 (b-32))
// NOTE: __launch_bounds__(256,2) — (256,4) caps VGPR at 64 and spills
// (R6: WRITE 52MB -> 6.5GB, k_outer 370 -> 2464 us). Do not raise.
// ---------------------------------------------------------------------------
__global__ __launch_bounds__(256, 2) void k_outer(const float* __restrict__ x,
                                                  const float* __restrict__ y,
                                                  float* __restrict__ pv,
                                                  float* __restrict__ pf,
                                                  int N, int cv, int cf)
{
    __shared__ f2 hs[PB][256];
    __shared__ float xs0[PB], xs1[PB], ys[PB];

    int bx = blockIdx.x;
    int t  = threadIdx.x;
    int ty = t >> 4, tx = t & 15;

    if (bx < 2 * cv) {
        int chunk = bx >> 1;
        int half64 = (bx & 1) * 64;
        int CP = (N + cv - 1) / cv;
        int n0 = chunk * CP, n1 = min(N, n0 + CP);

        f2 acc[4][8];
        #pragma unroll
        for (int i = 0; i < 4; ++i)
            #pragma unroll
            for (int j = 0; j < 8; ++j) acc[i][j] = (f2){0.f, 0.f};

        for (int s = n0; s < n1; s += PB) {
            int cnt = min(PB, n1 - s);
            __syncthreads();
            if (t < cnt) {
                xs0[t] = x[2 * (s + t)];
                xs1[t] = x[2 * (s + t) + 1];
            }
            __syncthreads();
            for (int p = 0; p < cnt; ++p) {
                f2 g;
                if (t < 128)
                    g = (t == 127) ? (f2){0.f, 0.f} : phasef(xs0[p], (float)t - 63.f, 1.f);
                else {
                    int c = t - 128;
                    g = (c == 127) ? (f2){0.f, 0.f} : phasef(xs1[p], (float)c - 63.f, 1.f);
                }
                hs[p][t] = g;
            }
            __syncthreads();
            for (int p = 0; p < cnt; ++p) {
                f2 h1[4], h2[8], h2s[8];
                #pragma unroll
                for (int i = 0; i < 4; ++i) h1[i] = hs[p][half64 + ty * 4 + i];
                #pragma unroll
                for (int j = 0; j < 8; ++j) {
                    f2 b = hs[p][128 + tx + 16 * j];
                    h2[j] = b;
                    h2s[j] = (f2){-b.y, b.x};
                }
                #pragma unroll
                for (int i = 0; i < 4; ++i)
                    #pragma unroll
                    for (int j = 0; j < 8; ++j) {
                        acc[i][j] = acc[i][j] + f2s(h1[i].x) * h2[j];
                        acc[i][j] = acc[i][j] + f2s(h1[i].y) * h2s[j];
                    }
            }
        }
        __syncthreads();
        f2* out = (f2*)pv + (size_t)chunk * 16384;
        #pragma unroll
        for (int i = 0; i < 4; ++i) {
            int a = half64 + ty * 4 + i;
            #pragma unroll
            for (int j = 0; j < 8; ++j)
                out[a * 128 + tx + 16 * j] = acc[i][j];
        }
    } else {
        int chunk = bx - 2 * cv;
        int CP = (N + cf - 1) / cf;
        int n0 = chunk * CP, n1 = min(N, n0 + CP);

        f2 acc[4][4];
        #pragma unroll
        for (int i = 0; i < 4; ++i)
            #pragma unroll
            for (int j = 0; j < 4; ++j) acc[i][j] = (f2){0.f, 0.f};

        for (int s = n0; s < n1; s += PB) {
            int cnt = min(PB, n1 - s);
            __syncthreads();
            if (t < cnt) {
                xs0[t] = x[2 * (s + t)];
                xs1[t] = x[2 * (s + t) + 1];
                ys[t]  = y[s + t];
            }
            __syncthreads();
            for (int p2 = 0; p2 < cnt; p2 += 2) {
                int p = p2 + (t >> 7);
                int c = t & 127;
                if (p < cnt) {
                    f2 g;
                    if (c < 64) g = phasef(xs0[p], (float)(32 - c), ys[p]);
                    else        g = phasef(xs1[p], (float)(32 - (c - 64)), 1.f);
                    hs[p][c] = g;
                }
            }
            __syncthreads();
            for (int p = 0; p < cnt; ++p) {
                f2 h1[4], h2[4], h2s[4];
                #pragma unroll
                for (int i = 0; i < 4; ++i) h1[i] = hs[p][ty * 4 + i];
                #pragma unroll
                for (int j = 0; j < 4; ++j) {
                    f2 b = hs[p][64 + tx + 16 * j];
                    h2[j] = b;
                    h2s[j] = (f2){-b.y, b.x};
                }
                #pragma unroll
                for (int i = 0; i < 4; ++i)
                    #pragma unroll
                    for (int j = 0; j < 4; ++j) {
                        acc[i][j] = acc[i][j] + f2s(h1[i].x) * h2[j];
                        acc[i][j] = acc[i][j] + f2s(h1[i].y) * h2s[j];
                    }
            }
        }
        __syncthreads();
        f2* out = (f2*)pf + (size_t)chunk * 4096;
        #pragma unroll
        for (int i = 0; i < 4; ++i) {
            int a = ty * 4 + i;
            #pragma unroll
            for (int j = 0; j < 4; ++j)
                out[a * 64 + tx + 16 * j] = acc[i][j];
        }
    }
}

// ---------------------------------------------------------------------------
// k_reduce: v partials sliced 8-way per element -> fp32 atomicAdd into
// vRf[(d1+64)*128 + (d2+64)] (zero-initialized; row/col 0 = pads). Fy
// partials serial per element (fp64) -> b = ws*Fy, init r0=p0=b, x0=0, rz0.
// ---------------------------------------------------------------------------
__global__ __launch_bounds__(256) void k_reduce(const float* __restrict__ pv,
                                                const float* __restrict__ pf,
                                                const float* __restrict__ wsv,
                                                float* __restrict__ vRf,
                                                double2* __restrict__ r0,
                                                double2* __restrict__ p0,
                                                double2* __restrict__ x0,
                                                double* __restrict__ scal,
                                                int cv, int cf)
{
    int id = blockIdx.x * 256 + threadIdx.x;
    if (id < 131072) {
        int e = id >> 3, sl = id & 7;
        int q1 = e >> 7, q2 = e & 127;
        if (q1 >= 1 && q2 >= 1) {
            int cn = cv >> 3;
            const float* src = pv + (size_t)((q1 - 1) * 128 + (q2 - 1)) * 2
                                  + (size_t)(sl * cn) * 32768;
            float sx = 0.f, sy = 0.f;
            for (int c = 0; c < cn; ++c) { sx += src[0]; sy += src[1]; src += 32768; }
            atomicAdd(&vRf[e * 2], sx);
            atomicAdd(&vRf[e * 2 + 1], sy);
        }
    } else {
        int e = id - 131072;          // 0..4095
        const float* s2p = pf + (size_t)e * 2;
        double fx = 0.0, fy2 = 0.0;
        for (int c = 0; c < cf; ++c) { fx += (double)s2p[0]; fy2 += (double)s2p[1]; s2p += 8192; }
        double w = (double)wsv[e];
        double2 bv = make_double2(w * fx, w * fy2);
        r0[e] = bv; p0[e] = bv; x0[e] = make_double2(0.0, 0.0);
        double rr = bv.x * bv.x + bv.y * bv.y;
        for (int off = 32; off > 0; off >>= 1) rr += __shfl_down(rr, off);
        if ((threadIdx.x & 63) == 0) atomicAdd(&scal[0], rr);
    }
}

// ---------------------------------------------------------------------------
// k_cg_iter: one full CG iteration, 256 blocks x 512 threads (8 waves).
//   t==0 recomputes alpha_{it-1}, beta_it from dot history (scal).
//   Replicated fp64 update -> z = ws*p_new stored fp32 in LDS (32 KB).
//   MV: wave w owns rows k = b*16 + 2w + {0,1}; lane = j2, loop j1; per j1
//   one 16B-contiguous vRf load covers both rows; fp32 pk-fma accumulate.
//   Wave-reduce over j2; lane 0 writes Ap/r/p/x (fp64) + dot partials.
//   scal: [0] = rz0; [1+3k..3+3k] = (pAp, rAp, ApAp) of iter k.
//   rz recurrence: rz+ = rz - 2a<r,Ap> + a^2|Ap|^2 (algebraically == ref).
// ---------------------------------------------------------------------------
__global__ __launch_bounds__(512) void k_cg_iter(
        const float* __restrict__ vRf, const float* __restrict__ wsv,
        const float* __restrict__ sig2,
        const double2* __restrict__ pin, double2* __restrict__ pout,
        const double2* __restrict__ rin, double2* __restrict__ rout,
        const double2* __restrict__ xin, double2* __restrict__ xout,
        const double2* __restrict__ apin, double2* __restrict__ apout,
        double* __restrict__ scal, int it)
{
    __shared__ f2 zs[4096];            // 32 KB fp32 z
    __shared__ double s_ab[2];
    __shared__ double redd[8][3];
    int b = blockIdx.x, t = threadIdx.x;

    if (t == 0) {
        double alpha = 0.0, beta = 0.0;
        if (it > 0) {
            double rz = scal[0], rzp = rz, alp = 0.0;
            for (int k = 0; k < it; ++k) {
                double pap = scal[1 + 3 * k], rap = scal[2 + 3 * k], apap = scal[3 + 3 * k];
                double al = rz / (pap + 1e-30);
                rzp = rz; alp = al;
                rz = fma(al, fma(al, apap, -2.0 * rap), rz);
            }
            alpha = alp; beta = rz / (rzp + 1e-30);
        }
        s_ab[0] = alpha; s_ab[1] = beta;
    }
    __syncthreads();
    double alpha = s_ab[0], beta = s_ab[1];

    // replicated update: z = ws * p_new (fp64 math, fp32 store)
    for (int s = 0; s < 8; ++s) {
        int i = t + 512 * s;
        double2 rv = rin[i];
        if (it > 0) {
            double2 ap = apin[i];
            rv.x -= alpha * ap.x; rv.y -= alpha * ap.y;
        }
        double2 pvv = pin[i];
        double2 pn = make_double2(rv.x + beta * pvv.x, rv.y + beta * pvv.y);
        double w = (double)wsv[i];
        zs[i] = (f2){(float)(w * pn.x), (float)(w * pn.y)};
    }
    __syncthreads();

    // fp32 Toeplitz MV: wave w -> rows k2b, k2b+1; lane = j2, loop j1
    int wv = t >> 6, j2 = t & 63;
    int k1 = b >> 2;
    int k2b = (b & 3) * 16 + wv * 2;
    f2 acc0 = (f2){0.f, 0.f}, acc1 = (f2){0.f, 0.f};
    const f2* vb = (const f2*)vRf + (k1 + 64) * 128 + (k2b - j2 + 64);
    const f2* zp = zs + j2;
    #pragma unroll 8
    for (int j1 = 0; j1 < 64; ++j1) {
        f2 zj = zp[j1 * 64];
        f2 zsw = (f2){-zj.y, zj.x};
        const f2* vr = vb - j1 * 128;
        f2 v0 = vr[0], v1 = vr[1];
        acc0 = acc0 + f2s(v0.x) * zj + f2s(v0.y) * zsw;
        acc1 = acc1 + f2s(v1.x) * zj + f2s(v1.y) * zsw;
    }

    #pragma unroll
    for (int off = 32; off > 0; off >>= 1) {
        acc0.x += __shfl_down(acc0.x, off);
        acc0.y += __shfl_down(acc0.y, off);
        acc1.x += __shfl_down(acc1.x, off);
        acc1.y += __shfl_down(acc1.y, off);
    }

    if (j2 == 0) {
        double s2 = (double)sig2[0];
        double d1 = 0.0, d2 = 0.0, d3 = 0.0;
        #pragma unroll
        for (int i = 0; i < 2; ++i) {
            int k = b * 16 + wv * 2 + i;
            double tx = (i == 0) ? (double)acc0.x : (double)acc1.x;
            double tyv = (i == 0) ? (double)acc0.y : (double)acc1.y;
            double2 rv = rin[k];
            if (it > 0) {
                double2 ap = apin[k];
                rv.x -= alpha * ap.x; rv.y -= alpha * ap.y;
            }
            double2 pvv = pin[k];
            double2 pn = make_double2(rv.x + beta * pvv.x, rv.y + beta * pvv.y);
            double w = (double)wsv[k];
            double2 apn = make_double2(w * tx + s2 * pn.x,
                                       w * tyv + s2 * pn.y);
            apout[k] = apn; rout[k] = rv; pout[k] = pn;
            double2 xv = xin[k];
            xout[k] = make_double2(xv.x + alpha * pvv.x, xv.y + alpha * pvv.y);
            d1 += pn.x * apn.x + pn.y * apn.y;
            d2 += rv.x * apn.x + rv.y * apn.y;
            d3 += apn.x * apn.x + apn.y * apn.y;
        }
        redd[wv][0] = d1; redd[wv][1] = d2; redd[wv][2] = d3;
    }
    __syncthreads();
    if (t == 0) {
        double a = 0.0, bb = 0.0, c = 0.0;
        for (int q = 0; q < 8; ++q) { a += redd[q][0]; bb += redd[q][1]; c += redd[q][2]; }
        atomicAdd(&scal[1 + 3 * it], a);
        atomicAdd(&scal[2 + 3 * it], bb);
        atomicAdd(&scal[3 + 3 * it], c);
    }
}

// ---------------------------------------------------------------------------
// k_eval: mu[b] = Re( sum_j e1[j] * sum_k alpha[j,k] e2[k] ),
// alpha = ws * (x_49 + alpha_49 * p_49)  (final CG update folded in).
// ---------------------------------------------------------------------------
__global__ __launch_bounds__(64) void k_eval(const float* __restrict__ xnew,
                                             const float* __restrict__ wsv,
                                             const double2* __restrict__ xsol,
                                             const double2* __restrict__ psol,
                                             const double* __restrict__ scal,
                                             float* __restrict__ out, int B)
{
    __shared__ float2 al[4096];
    __shared__ double s_al;
    int t = threadIdx.x;
    int b = blockIdx.x * 64 + t;
    if (t == 0) {
        double rz = scal[0], alp = 0.0;
        for (int k = 0; k < 50; ++k) {
            double pap = scal[1 + 3 * k], rap = scal[2 + 3 * k], apap = scal[3 + 3 * k];
            double a2 = rz / (pap + 1e-30);
            alp = a2;
            rz = fma(a2, fma(a2, apap, -2.0 * rap), rz);
        }
        s_al = alp;
    }
    __syncthreads();
    double alpha49 = s_al;
    for (int i = t; i < 4096; i += 64) {
        double2 xv = xsol[i];
        double2 pv = psol[i];
        double w = (double)wsv[i];
        al[i] = make_float2((float)(w * (xv.x + alpha49 * pv.x)),
                            (float)(w * (xv.y + alpha49 * pv.y)));
    }
    float x0 = 0.f, x1 = 0.f;
    if (b < B) { x0 = xnew[2 * b]; x1 = xnew[2 * b + 1]; }
    __syncthreads();
    double2 wstep; { double sn, cs; sincospi((double)x1, &sn, &cs); wstep = make_double2(cs, sn); }
    double mu = 0.0;
    for (int jg = 0; jg < 4; ++jg) {
        float2 tacc[16];
        for (int q = 0; q < 16; ++q) tacc[q] = make_float2(0.f, 0.f);
        double2 e2; { double sn, cs; sincospi(-32.0 * (double)x1, &sn, &cs); e2 = make_double2(cs, sn); }
        for (int k = 0; k < 64; ++k) {
            float2 e2f = make_float2((float)e2.x, (float)e2.y);
            for (int q = 0; q < 16; ++q) {
                int j = jg * 16 + q;
                float2 a = al[j * 64 + k];
                tacc[q].x += a.x * e2f.x - a.y * e2f.y;
                tacc[q].y += a.x * e2f.y + a.y * e2f.x;
            }
            e2 = make_double2(e2.x * wstep.x - e2.y * wstep.y,
                              e2.x * wstep.y + e2.y * wstep.x);
        }
        for (int q = 0; q < 16; ++q) {
            int j = jg * 16 + q;
            double sn, cs;
            sincospi((double)x0 * (double)(j - 32), &sn, &cs);
            mu += cs * (double)tacc[q].x - sn * (double)tacc[q].y;
        }
    }
    if (b < B) out[b] = (float)mu;
}

// ---------------------------------------------------------------------------

extern "C" void kernel_launch(void* const* d_in, const int* in_sizes, int n_in,
                              void* d_out, int out_size, void* d_ws, size_t ws_size,
                              hipStream_t stream)
{
    const float* x    = (const float*)d_in[0];
    const float* y    = (const float*)d_in[1];
    const float* xnew = (const float*)d_in[2];
    const float* wsv  = (const float*)d_in[3];
    const float* sig2 = (const float*)d_in[4];
    int N = in_sizes[1];
    int B = in_sizes[2] / 2;

    char* base = (char*)d_ws;
    size_t o = 0;
    float*  vRf  = (float*)(base + o);   o += 131072;    // 128x128 fp32 Toeplitz
    double* scal = (double*)(base + o);  o += 4096;      // [0]=rz0, then 50 triples
    double2* rb[2], *pb[2], *xb[2], *ab[2];
    for (int q = 0; q < 2; ++q) { rb[q] = (double2*)(base + o); o += 65536; }
    for (int q = 0; q < 2; ++q) { pb[q] = (double2*)(base + o); o += 65536; }
    for (int q = 0; q < 2; ++q) { xb[q] = (double2*)(base + o); o += 65536; }
    for (int q = 0; q < 2; ++q) { ab[q] = (double2*)(base + o); o += 65536; }
    size_t avail = (ws_size > o) ? ws_size - o : 0;
    int cv = (int)(avail / 139264);                      // 128KB v + 8KB fy per unit
    if (cv > 384) cv = 384;
    if (cv < 16) cv = 16;
    cv &= ~15;                                           // cv%8==0, cf%4==0
    int cf = cv / 4;
    float* pv = (float*)(base + o); o += (size_t)cv * 131072;
    float* pf = (float*)(base + o);

    hipMemsetAsync(vRf, 0, 131072 + 4096, stream);       // vRf + scal contiguous

    k_outer<<<2 * cv + cf, 256, 0, stream>>>(x, y, pv, pf, N, cv, cf);
    k_reduce<<<528, 256, 0, stream>>>(pv, pf, wsv, vRf,
                                      rb[0], pb[0], xb[0], scal, cv, cf);

    for (int it = 0; it < 50; ++it) {
        int in = it & 1, op = in ^ 1;
        k_cg_iter<<<256, 512, 0, stream>>>(vRf, wsv, sig2,
                                           pb[in], pb[op], rb[in], rb[op],
                                           xb[in], xb[op], ab[in], ab[op],
                                           scal, it);
    }
    // after it=49: final state (x_49, p_49) in parity-0 buffers
    k_eval<<<(B + 63) / 64, 64, 0, stream>>>(xnew, wsv, xb[0], pb[0], scal,
                                             (float*)d_out, B);
}